// Round 8
// baseline (312.875 us; speedup 1.0000x reference)
//
#include <hip/hip_runtime.h>
#include <stdint.h>

// B=16, C=64, H=128, W=128, HX=HY=64. All I/O fp32.
// Pipeline (3 kernels):
//   k_proj0 : pre_x[t=w][seq=(b,h)][j] (f16, incl bias) = Wihx·x + b   (bf16 hi/lo)
//   k_scan<0>: X recurrence; FUSED Y-projection -> pre_y[t=h][seq=(b,w)][j] (f16, incl bias)
//   k_scan<1>: Y recurrence -> out[b][j][h][w] fp32
// d_ws: pre_x (33.5MB) + pre_y (33.5MB) = 67MB.
// ROUND 8: F16 DUAL-CHAIN 4-WAVE. Cost model from rounds 6/7:
//   r6 (4 waves, 4 vals/lane, LDS+barrier) = 388 ns/step   <- per-wave issue small
//   r7 (1 wave, 16 vals/lane, no barrier)  = 508 ns/step   <- issue serialization dominates
// => per-wave issue work + its dependency stalls are the cost; the barrier is minor.
// Fix: TWO chains per 4-wave block (64 blocks x 256 thr), shared Whh/Wy frags,
// per-chain B-frags + LDS planes, ONE __syncthreads per tick for both chains.
// The chains' independent MFMA/tanh streams fill each other's dependency
// stalls; worst case (full serialization) still amortizes barrier+ds latency.
// This is round 2's structure in the f16 era: r2 failed at ~170-need/148-grant
// hi/lo pressure; f16 needs ~140 -> fits the historical 256-thr grant.

#define TLEN 128
#define NSEQ 2048
#define PSH (NSEQ*64)   // f16 elems per t-slice
#define GT 8            // steps per group

typedef __bf16   bf16x8 __attribute__((ext_vector_type(8)));
typedef _Float16 f16x8  __attribute__((ext_vector_type(8)));
typedef _Float16 f16x4  __attribute__((ext_vector_type(4)));
typedef float    f32x4  __attribute__((ext_vector_type(4)));
typedef unsigned short u16x4 __attribute__((ext_vector_type(4)));

static __device__ __forceinline__ unsigned int fbits(float f){
    union { float f; unsigned int u; } v; v.f = f; return v.u;
}
static __device__ __forceinline__ float ubits(unsigned int u){
    union { unsigned int u; float f; } v; v.u = u; return v.f;
}
static __device__ __forceinline__ float bf2f(unsigned short s){ return ubits(((unsigned int)s) << 16); }
static __device__ __forceinline__ unsigned short f2bf(float f){
    unsigned int u = fbits(f);
    return (unsigned short)((u + 0x7FFFu + ((u >> 16) & 1u)) >> 16);
}
static __device__ __forceinline__ __bf16 us2b(unsigned short s){
    union { unsigned short u; __bf16 b; } v; v.u = s; return v.b;
}
static __device__ __forceinline__ unsigned short h2us(_Float16 h){
    union { _Float16 h; unsigned short s; } v; v.h = h; return v.s;
}
struct bfpair { __bf16 hi, lo; };
static __device__ __forceinline__ bfpair splitf(float f){   // RNE split (weights, once)
    unsigned short h = f2bf(f);
    bfpair r; r.hi = us2b(h); r.lo = us2b(f2bf(f - bf2f(h))); return r;
}
static __device__ __forceinline__ float fast_tanh(float x){
    float e = __builtin_amdgcn_exp2f(x * 2.8853900817779268f);
    return 1.0f - 2.0f * __builtin_amdgcn_rcpf(e + 1.0f);
}

// ---------------------------------------------------------------------------
// k_proj0: pre_x[w][b*128+h][j] = f16( sum_c x[b][c][h][w]*Wihx[j][c] + bias )
// bf16 hi/lo 3-term MFMA. Block 256thr/4 waves; wave: 32 rows x 64 j.
__global__ __launch_bounds__(256) void k_proj0(const float* __restrict__ A,
                                               const float* __restrict__ Wih,
                                               const float* __restrict__ b1,
                                               const float* __restrict__ b2,
                                               _Float16* __restrict__ pre){
    int lane = threadIdx.x & 63;
    int wv   = threadIdx.x >> 6;
    int q    = lane >> 4, l15 = lane & 15;

    bf16x8 Whi[4][2], Wlo[4][2];
#pragma unroll
    for (int n = 0; n < 4; n++)
#pragma unroll
        for (int kc = 0; kc < 2; kc++){
            const float* p = Wih + (n * 16 + l15) * 64 + kc * 32 + q * 8;
#pragma unroll
            for (int i = 0; i < 8; i++){
                bfpair s = splitf(p[i]);
                Whi[n][kc][i] = s.hi; Wlo[n][kc][i] = s.lo;
            }
        }
    float bias[4];
#pragma unroll
    for (int n = 0; n < 4; n++){
        int j = n * 16 + l15;
        bias[n] = b1[j] + b2[j];
    }

    int row0 = blockIdx.x * 128 + wv * 32;

    float av[2][2][8];
#pragma unroll
    for (int mi = 0; mi < 2; mi++){
        int r = row0 + mi * 16 + l15;
        int b = r >> 14, hw = r & 16383;
        const float* xb = A + (size_t)b * 1048576 + hw;
#pragma unroll
        for (int kc = 0; kc < 2; kc++)
#pragma unroll
            for (int i = 0; i < 8; i++)
                av[mi][kc][i] = xb[(size_t)(kc * 32 + q * 8 + i) * 16384];
    }

#pragma unroll
    for (int mi = 0; mi < 2; mi++){
        int rb = row0 + mi * 16;
        bf16x8 Ahi[2], Alo[2];
#pragma unroll
        for (int kc = 0; kc < 2; kc++)
#pragma unroll
            for (int i = 0; i < 8; i++){
                bfpair s = splitf(av[mi][kc][i]);
                Ahi[kc][i] = s.hi; Alo[kc][i] = s.lo;
            }
        f32x4 acc[4];
#pragma unroll
        for (int n = 0; n < 4; n++) acc[n] = (f32x4){bias[n], bias[n], bias[n], bias[n]};
#pragma unroll
        for (int n = 0; n < 4; n++)
#pragma unroll
            for (int kc = 0; kc < 2; kc++){
                acc[n] = __builtin_amdgcn_mfma_f32_16x16x32_bf16(Ahi[kc], Whi[n][kc], acc[n], 0, 0, 0);
                acc[n] = __builtin_amdgcn_mfma_f32_16x16x32_bf16(Alo[kc], Whi[n][kc], acc[n], 0, 0, 0);
                acc[n] = __builtin_amdgcn_mfma_f32_16x16x32_bf16(Ahi[kc], Wlo[n][kc], acc[n], 0, 0, 0);
            }
        // rows rb..rb+15 share (b,h); w = (rb&127) + q*4 + rr. seq_x = b*128+h.
        int bT = rb >> 14, hT = (rb >> 7) & 127, wBase = rb & 127;
        size_t seqOff = (size_t)bT * 128 + hT;
#pragma unroll
        for (int n = 0; n < 4; n++)
#pragma unroll
            for (int rr = 0; rr < 4; rr++){
                int w = wBase + q * 4 + rr;
                pre[((size_t)w * NSEQ + seqOff) * 64 + n * 16 + l15] = (_Float16)acc[n][rr];
            }
    }
}

// ---------------------------------------------------------------------------
// k_scan<PASS>: h_t = tanh(pre_t + Whh h_{t-1}), 64 blocks x 4 waves.
// Block owns TWO chains (c=0: seqs n0..+15, c=1: n0+16..+31). Wave wv owns
// j-tile [wv*16,+16) for BOTH chains; Whh/Wy f16 frags shared (chain-
// invariant). Per tick: both chains' {cvt, 2 rec MFMA, (PASS0) 2 Y MFMA,
// 4 tanh, pack, ds_write} are independent straight-line streams -> the
// scheduler interleaves them, filling each chain's ds/MFMA/tanh dependency
// stalls; ONE __syncthreads serves both. h exchanged via swizzled LDS
// (per-chain plane, parity dbuf). pre slab (GT steps x 2 chains) loaded at
// group top; outputs staged in regs, burst-stored at group end -> barriers
// stay vmcnt-clean.
// PASS 0: fused Y-proj on B (h_{t-1}) -> pre_y[t-1] f16 (incl bias_y) + tail.
// PASS 1: final out[b][j][t][w] fp32.
template<int PASS>
__global__ __launch_bounds__(256) void k_scan(const _Float16* __restrict__ pre,
                                              const float* __restrict__ Whh,
                                              const float* __restrict__ Wy,
                                              const float* __restrict__ by1,
                                              const float* __restrict__ by2,
                                              _Float16* __restrict__ prey,
                                              float* __restrict__ outf){
    __shared__ alignas(16) unsigned short hbuf[2][2][16][64];  // [chain][par][seq][j] f16 bits
    int lane = threadIdx.x & 63;
    int wv   = threadIdx.x >> 6;
    int q = lane >> 4, l15 = lane & 15;
    int n0 = blockIdx.x * 32;
    int j0 = wv * 16 + q * 4;

    f16x8 Af[2];
#pragma unroll
    for (int kc = 0; kc < 2; kc++){
        const float* p = Whh + (wv * 16 + l15) * 64 + kc * 32 + q * 8;
#pragma unroll
        for (int i = 0; i < 8; i++)
            Af[kc][i] = (_Float16)p[i];
    }
    f16x8 Yf[2];
    f32x4 biasy = (f32x4){0.f, 0.f, 0.f, 0.f};
    if constexpr (PASS == 0){
#pragma unroll
        for (int kc = 0; kc < 2; kc++){
            const float* p = Wy + (wv * 16 + l15) * 64 + kc * 32 + q * 8;
#pragma unroll
            for (int i = 0; i < 8; i++)
                Yf[kc][i] = (_Float16)p[i];
        }
#pragma unroll
        for (int r = 0; r < 4; r++) biasy[r] = by1[j0 + r] + by2[j0 + r];
    }

    f16x8 Bf[2][2];   // [chain][kc]
#pragma unroll
    for (int c = 0; c < 2; c++)
#pragma unroll
        for (int kc = 0; kc < 2; kc++)
#pragma unroll
            for (int i = 0; i < 8; i++) Bf[c][kc][i] = (_Float16)0.f;

    int bb = n0 >> 7, low7 = n0 & 127;   // n0 multiple of 32: c*16+l15 stays in 128-block

    const _Float16* pb[2];
    size_t spy[2];
#pragma unroll
    for (int c = 0; c < 2; c++){
        pb[c]  = pre + (size_t)(n0 + c * 16 + l15) * 64 + j0;
        spy[c] = (size_t)(low7 + c * 16 + l15) * NSEQ + (size_t)bb * 128;
    }

    int e   = l15 & 7;
    int wj  = (((j0 >> 3) ^ e) << 3) | (j0 & 7);
    int rj0 = ((q)     ^ e) << 3;
    int rj1 = ((4 + q) ^ e) << 3;

    f16x4 ps[2][GT];
    u16x4 prey_st[2][GT];
    f32x4 outst[2][GT];

    for (int g = 0; g < TLEN / GT; g++){
        int G = g * GT;
#pragma unroll
        for (int c = 0; c < 2; c++)
#pragma unroll
            for (int u = 0; u < GT; u++)
                ps[c][u] = *(const f16x4*)(pb[c] + (size_t)(G + u) * PSH);

#pragma unroll
        for (int u = 0; u < GT; u++){
            int t = G + u;
            int par = t & 1;
            // ---- both chains' step bodies: fully independent streams,
            //      scheduler interleaves (pressure ~140 fits 256-thr grant)
#pragma unroll
            for (int c = 0; c < 2; c++){
                f32x4 a = (f32x4){(float)ps[c][u][0], (float)ps[c][u][1],
                                  (float)ps[c][u][2], (float)ps[c][u][3]};
                a = __builtin_amdgcn_mfma_f32_16x16x32_f16(Af[0], Bf[c][0], a, 0, 0, 0);
                a = __builtin_amdgcn_mfma_f32_16x16x32_f16(Af[1], Bf[c][1], a, 0, 0, 0);
                if constexpr (PASS == 0){
                    f32x4 y = biasy;
                    y = __builtin_amdgcn_mfma_f32_16x16x32_f16(Yf[0], Bf[c][0], y, 0, 0, 0);
                    y = __builtin_amdgcn_mfma_f32_16x16x32_f16(Yf[1], Bf[c][1], y, 0, 0, 0);
#pragma unroll
                    for (int r = 0; r < 4; r++)
                        prey_st[c][u][r] = h2us((_Float16)y[r]);
                }
                u16x4 h4;
#pragma unroll
                for (int r = 0; r < 4; r++){
                    float tv = fast_tanh(a[r]);
                    if constexpr (PASS == 1) outst[c][u][r] = tv;
                    h4[r] = h2us((_Float16)tv);
                }
                *(u16x4*)&hbuf[c][par][l15][wj] = h4;
            }
            __syncthreads();
#pragma unroll
            for (int c = 0; c < 2; c++){
                Bf[c][0] = *(const f16x8*)&hbuf[c][par][l15][rj0];
                Bf[c][1] = *(const f16x8*)&hbuf[c][par][l15][rj1];
            }
        }
        // ---- burst stores (drained once at next group's first barrier)
        if constexpr (PASS == 0){
#pragma unroll
            for (int c = 0; c < 2; c++)
#pragma unroll
                for (int u = 0; u < GT; u++){
                    int tp = G - 1 + u;
                    if (tp >= 0)
                        *(u16x4*)(prey + (spy[c] + tp) * 64 + j0) = prey_st[c][u];
                }
        } else {
#pragma unroll
            for (int c = 0; c < 2; c++)
#pragma unroll
                for (int u = 0; u < GT; u++)
#pragma unroll
                    for (int r = 0; r < 4; r++)
                        outf[((size_t)(bb * 64 + j0 + r) * TLEN + (G + u)) * 128
                             + low7 + c * 16 + l15] = outst[c][u][r];
        }
    }
    // tail: pre_y[127] from final B (= h_127), both chains
    if constexpr (PASS == 0){
#pragma unroll
        for (int c = 0; c < 2; c++){
            f32x4 y = biasy;
            y = __builtin_amdgcn_mfma_f32_16x16x32_f16(Yf[0], Bf[c][0], y, 0, 0, 0);
            y = __builtin_amdgcn_mfma_f32_16x16x32_f16(Yf[1], Bf[c][1], y, 0, 0, 0);
            u16x4 pv;
#pragma unroll
            for (int r = 0; r < 4; r++)
                pv[r] = h2us((_Float16)y[r]);
            *(u16x4*)(prey + (spy[c] + (TLEN - 1)) * 64 + j0) = pv;
        }
    }
}

// ---------------------------------------------------------------------------
extern "C" void kernel_launch(void* const* d_in, const int* in_sizes, int n_in,
                              void* d_out, int out_size, void* d_ws, size_t ws_size,
                              hipStream_t stream){
    (void)in_sizes; (void)n_in; (void)out_size; (void)ws_size;
    const float* x    = (const float*)d_in[0];
    const float* Wihx = (const float*)d_in[1];
    const float* Whhx = (const float*)d_in[2];
    const float* bihx = (const float*)d_in[3];
    const float* bhhx = (const float*)d_in[4];
    const float* Wihy = (const float*)d_in[5];
    const float* Whhy = (const float*)d_in[6];
    const float* bihy = (const float*)d_in[7];
    const float* bhhy = (const float*)d_in[8];
    _Float16* prex = (_Float16*)d_ws;                          // 33.5MB
    _Float16* prey = prex + (size_t)NSEQ * TLEN * 64;          // 33.5MB
    float* of = (float*)d_out;

    k_proj0 <<<2048, 256, 0, stream>>>(x, Wihx, bihx, bhhx, prex);
    k_scan<0><<<64, 256, 0, stream>>>(prex, Whhx, Wihy, bihy, bhhy, prey, nullptr);
    k_scan<1><<<64, 256, 0, stream>>>(prey, Whhy, nullptr, nullptr, nullptr, nullptr, of);
}

// Round 9
// 227.788 us; speedup vs baseline: 1.3735x; 1.3735x over previous
//
#include <hip/hip_runtime.h>
#include <stdint.h>

// B=16, C=64, H=128, W=128, HX=HY=64. All I/O fp32.
// Pipeline (3 kernels):
//   k_proj0 : pre_x[t=w][seq=(b,h)][j] (f16, incl bias) = Wihx·x + b   (bf16 hi/lo)
//   k_scan<0>: X recurrence; FUSED Y-projection -> pre_y[t=h][seq=(b,w)][j] (f16, incl bias)
//   k_scan<1>: Y recurrence -> out[b][j][h][w] fp32
// d_ws: pre_x (33.5MB) + pre_y (33.5MB) = 67MB.
// ROUND 9: scans = round-6 champion, byte-identical (388ns/tick; every
// parallelism axis measured dead: r1/3/5 allocator sandbags 512-thr blocks,
// r2/4/8 scheduler serializes multi-chain straight-line code, r7 single-wave
// issue-serializes). New: k_proj0 STORE COALESCING. Old path: 32 scalar 2B
// stores/lane, 16-lane groups touching 4x32B fragments of 128B lines 512KB
// apart (~4x write amplification). New path: per-wave LDS transpose (16
// ds_write_b16 -> 2 ds_read_b128 -> 2 global dwordx4 bursts, 8 lanes = one
// dense 128B row of pre[w][seq][:]). Intra-wave LDS RAW: no barrier needed.
// Rounding path bit-identical.

#define TLEN 128
#define NSEQ 2048
#define PSH (NSEQ*64)   // f16 elems per t-slice
#define GT 16           // steps per group

typedef __bf16   bf16x8 __attribute__((ext_vector_type(8)));
typedef _Float16 f16x8  __attribute__((ext_vector_type(8)));
typedef _Float16 f16x4  __attribute__((ext_vector_type(4)));
typedef float    f32x4  __attribute__((ext_vector_type(4)));
typedef unsigned short u16x4 __attribute__((ext_vector_type(4)));
typedef unsigned short u16x8 __attribute__((ext_vector_type(8)));

static __device__ __forceinline__ unsigned int fbits(float f){
    union { float f; unsigned int u; } v; v.f = f; return v.u;
}
static __device__ __forceinline__ float ubits(unsigned int u){
    union { unsigned int u; float f; } v; v.u = u; return v.f;
}
static __device__ __forceinline__ float bf2f(unsigned short s){ return ubits(((unsigned int)s) << 16); }
static __device__ __forceinline__ unsigned short f2bf(float f){
    unsigned int u = fbits(f);
    return (unsigned short)((u + 0x7FFFu + ((u >> 16) & 1u)) >> 16);
}
static __device__ __forceinline__ __bf16 us2b(unsigned short s){
    union { unsigned short u; __bf16 b; } v; v.u = s; return v.b;
}
static __device__ __forceinline__ unsigned short h2us(_Float16 h){
    union { _Float16 h; unsigned short s; } v; v.h = h; return v.s;
}
struct bfpair { __bf16 hi, lo; };
static __device__ __forceinline__ bfpair splitf(float f){   // RNE split (weights, once)
    unsigned short h = f2bf(f);
    bfpair r; r.hi = us2b(h); r.lo = us2b(f2bf(f - bf2f(h))); return r;
}
static __device__ __forceinline__ float fast_tanh(float x){
    float e = __builtin_amdgcn_exp2f(x * 2.8853900817779268f);
    return 1.0f - 2.0f * __builtin_amdgcn_rcpf(e + 1.0f);
}

// ---------------------------------------------------------------------------
// k_proj0: pre_x[w][b*128+h][j] = f16( sum_c x[b][c][h][w]*Wihx[j][c] + bias )
// bf16 hi/lo 3-term MFMA. Block 256thr/4 waves; wave: 32 rows (= 2 mi-tiles
// of 16 consecutive w, fixed seq) x 64 j. Stores via per-wave LDS transpose:
// each mi-tile (16w x 64j, 2KB) staged in lds_t[mi][wv], read back u16x8 and
// stored as dense 128B rows (2 dwordx4 bursts per tile).
__global__ __launch_bounds__(256) void k_proj0(const float* __restrict__ A,
                                               const float* __restrict__ Wih,
                                               const float* __restrict__ b1,
                                               const float* __restrict__ b2,
                                               _Float16* __restrict__ pre){
    __shared__ alignas(16) unsigned short lds_t[2][4][16][64];  // [mi][wave][w'][j]
    int lane = threadIdx.x & 63;
    int wv   = threadIdx.x >> 6;
    int q    = lane >> 4, l15 = lane & 15;

    bf16x8 Whi[4][2], Wlo[4][2];
#pragma unroll
    for (int n = 0; n < 4; n++)
#pragma unroll
        for (int kc = 0; kc < 2; kc++){
            const float* p = Wih + (n * 16 + l15) * 64 + kc * 32 + q * 8;
#pragma unroll
            for (int i = 0; i < 8; i++){
                bfpair s = splitf(p[i]);
                Whi[n][kc][i] = s.hi; Wlo[n][kc][i] = s.lo;
            }
        }
    float bias[4];
#pragma unroll
    for (int n = 0; n < 4; n++){
        int j = n * 16 + l15;
        bias[n] = b1[j] + b2[j];
    }

    int row0 = blockIdx.x * 128 + wv * 32;

    float av[2][2][8];
#pragma unroll
    for (int mi = 0; mi < 2; mi++){
        int r = row0 + mi * 16 + l15;
        int b = r >> 14, hw = r & 16383;
        const float* xb = A + (size_t)b * 1048576 + hw;
#pragma unroll
        for (int kc = 0; kc < 2; kc++)
#pragma unroll
            for (int i = 0; i < 8; i++)
                av[mi][kc][i] = xb[(size_t)(kc * 32 + q * 8 + i) * 16384];
    }

#pragma unroll
    for (int mi = 0; mi < 2; mi++){
        int rb = row0 + mi * 16;
        bf16x8 Ahi[2], Alo[2];
#pragma unroll
        for (int kc = 0; kc < 2; kc++)
#pragma unroll
            for (int i = 0; i < 8; i++){
                bfpair s = splitf(av[mi][kc][i]);
                Ahi[kc][i] = s.hi; Alo[kc][i] = s.lo;
            }
        f32x4 acc[4];
#pragma unroll
        for (int n = 0; n < 4; n++) acc[n] = (f32x4){bias[n], bias[n], bias[n], bias[n]};
#pragma unroll
        for (int n = 0; n < 4; n++)
#pragma unroll
            for (int kc = 0; kc < 2; kc++){
                acc[n] = __builtin_amdgcn_mfma_f32_16x16x32_bf16(Ahi[kc], Whi[n][kc], acc[n], 0, 0, 0);
                acc[n] = __builtin_amdgcn_mfma_f32_16x16x32_bf16(Alo[kc], Whi[n][kc], acc[n], 0, 0, 0);
                acc[n] = __builtin_amdgcn_mfma_f32_16x16x32_bf16(Ahi[kc], Wlo[n][kc], acc[n], 0, 0, 0);
            }
        // rows rb..rb+15 share (b,h) = seq; w = (rb&127) + q*4 + rr.
        int bT = rb >> 14, hT = (rb >> 7) & 127, wBase = rb & 127;
        size_t seqOff = (size_t)bT * 128 + hT;
        // stage tile in per-wave LDS: [w' = q*4+rr][j = n*16+l15]
#pragma unroll
        for (int n = 0; n < 4; n++)
#pragma unroll
            for (int rr = 0; rr < 4; rr++)
                lds_t[mi][wv][q * 4 + rr][n * 16 + l15] = h2us((_Float16)acc[n][rr]);
        // read back transposed: lane covers (w' = lane>>3 + 8k, j8 = (lane&7)*8)
        // -> 8 consecutive lanes write one dense 128B row of pre[w][seq][:]
#pragma unroll
        for (int k = 0; k < 2; k++){
            int wp = (lane >> 3) + k * 8;
            int j8 = (lane & 7) * 8;
            u16x8 v = *(const u16x8*)&lds_t[mi][wv][wp][j8];
            *(u16x8*)(pre + ((size_t)(wBase + wp) * NSEQ + seqOff) * 64 + j8) = v;
        }
    }
}

// ---------------------------------------------------------------------------
// k_scan<PASS>: h_t = tanh(pre_t + Whh h_{t-1}), 128 blocks x 4 waves.
// (ROUND-6 CHAMPION, unchanged.) Wave wv owns j-tile [wv*16,+16). Whh/Wy f16
// A-frags in VGPRs. h carried as f16. Per step: 2 rec MFMA (+2 Y MFMA PASS0),
// 4 tanh, single u16 LDS plane exchange (swizzled, parity dbuf) + one
// __syncthreads. pre slab (GT steps) reg-loaded at group top; outputs staged
// and burst-stored at group end -> barriers stay vmcnt-clean.
template<int PASS>
__global__ __launch_bounds__(256) void k_scan(const _Float16* __restrict__ pre,
                                              const float* __restrict__ Whh,
                                              const float* __restrict__ Wy,
                                              const float* __restrict__ by1,
                                              const float* __restrict__ by2,
                                              _Float16* __restrict__ prey,
                                              float* __restrict__ outf){
    __shared__ alignas(16) unsigned short hbuf[2][16][64];  // [par][seq][j] f16 bits
    int lane = threadIdx.x & 63;
    int wv   = threadIdx.x >> 6;
    int q = lane >> 4, l15 = lane & 15;
    int n0 = blockIdx.x * 16;
    int j0 = wv * 16 + q * 4;

    f16x8 Af[2];
#pragma unroll
    for (int kc = 0; kc < 2; kc++){
        const float* p = Whh + (wv * 16 + l15) * 64 + kc * 32 + q * 8;
#pragma unroll
        for (int i = 0; i < 8; i++)
            Af[kc][i] = (_Float16)p[i];
    }
    f16x8 Yf[2];
    f32x4 biasy = (f32x4){0.f, 0.f, 0.f, 0.f};
    if constexpr (PASS == 0){
#pragma unroll
        for (int kc = 0; kc < 2; kc++){
            const float* p = Wy + (wv * 16 + l15) * 64 + kc * 32 + q * 8;
#pragma unroll
            for (int i = 0; i < 8; i++)
                Yf[kc][i] = (_Float16)p[i];
        }
#pragma unroll
        for (int r = 0; r < 4; r++) biasy[r] = by1[j0 + r] + by2[j0 + r];
    }

    f16x8 Bf[2];
#pragma unroll
    for (int kc = 0; kc < 2; kc++)
#pragma unroll
        for (int i = 0; i < 8; i++) Bf[kc][i] = (_Float16)0.f;

    int bb = n0 >> 7, low7 = n0 & 127;   // PASS0: h0 = low7; PASS1: w0 = low7

    const _Float16* pb = pre + (size_t)(n0 + l15) * 64 + j0;
    size_t spy = (size_t)(low7 + l15) * NSEQ + (size_t)bb * 128;  // PASS0 prey seq base

    int e   = l15 & 7;
    int wj  = (((j0 >> 3) ^ e) << 3) | (j0 & 7);
    int rj0 = ((q)     ^ e) << 3;
    int rj1 = ((4 + q) ^ e) << 3;

    f16x4 ps[GT];
    u16x4 prey_st[GT];
    f32x4 outst[GT];

    for (int g = 0; g < TLEN / GT; g++){
        int G = g * GT;
#pragma unroll
        for (int u = 0; u < GT; u++)
            ps[u] = *(const f16x4*)(pb + (size_t)(G + u) * PSH);

#pragma unroll
        for (int u = 0; u < GT; u++){
            int t = G + u;
            // ---- recurrence: 2 chained f16 MFMAs (critical path)
            f32x4 a = (f32x4){(float)ps[u][0], (float)ps[u][1], (float)ps[u][2], (float)ps[u][3]};
            a = __builtin_amdgcn_mfma_f32_16x16x32_f16(Af[0], Bf[0], a, 0, 0, 0);
            a = __builtin_amdgcn_mfma_f32_16x16x32_f16(Af[1], Bf[1], a, 0, 0, 0);
            // ---- fused Y-proj on current B (= h_{t-1}) -> pre_y[t-1];
            //      independent of the a-chain, fills its latency window
            if constexpr (PASS == 0){
                f32x4 y = biasy;
                y = __builtin_amdgcn_mfma_f32_16x16x32_f16(Yf[0], Bf[0], y, 0, 0, 0);
                y = __builtin_amdgcn_mfma_f32_16x16x32_f16(Yf[1], Bf[1], y, 0, 0, 0);
#pragma unroll
                for (int r = 0; r < 4; r++)
                    prey_st[u][r] = h2us((_Float16)y[r]);
            }

            u16x4 h4;
#pragma unroll
            for (int r = 0; r < 4; r++){
                float tv = fast_tanh(a[r]);
                if constexpr (PASS == 1) outst[u][r] = tv;
                h4[r] = h2us((_Float16)tv);
            }
            int par = t & 1;
            *(u16x4*)&hbuf[par][l15][wj] = h4;
            __syncthreads();
            Bf[0] = *(const f16x8*)&hbuf[par][l15][rj0];
            Bf[1] = *(const f16x8*)&hbuf[par][l15][rj1];
        }
        // ---- burst stores (drained once at next group's first barrier)
        if constexpr (PASS == 0){
#pragma unroll
            for (int u = 0; u < GT; u++){
                int tp = G - 1 + u;
                if (tp >= 0)
                    *(u16x4*)(prey + (spy + tp) * 64 + j0) = prey_st[u];
            }
        } else {
#pragma unroll
            for (int u = 0; u < GT; u++)
#pragma unroll
                for (int r = 0; r < 4; r++)
                    outf[((size_t)(bb * 64 + j0 + r) * TLEN + (G + u)) * 128 + low7 + l15] = outst[u][r];
        }
    }
    // tail: pre_y[127] from final B (= h_127)
    if constexpr (PASS == 0){
        f32x4 y = biasy;
        y = __builtin_amdgcn_mfma_f32_16x16x32_f16(Yf[0], Bf[0], y, 0, 0, 0);
        y = __builtin_amdgcn_mfma_f32_16x16x32_f16(Yf[1], Bf[1], y, 0, 0, 0);
        u16x4 pv;
#pragma unroll
        for (int r = 0; r < 4; r++)
            pv[r] = h2us((_Float16)y[r]);
        *(u16x4*)(prey + (spy + (TLEN - 1)) * 64 + j0) = pv;
    }
}

// ---------------------------------------------------------------------------
extern "C" void kernel_launch(void* const* d_in, const int* in_sizes, int n_in,
                              void* d_out, int out_size, void* d_ws, size_t ws_size,
                              hipStream_t stream){
    (void)in_sizes; (void)n_in; (void)out_size; (void)ws_size;
    const float* x    = (const float*)d_in[0];
    const float* Wihx = (const float*)d_in[1];
    const float* Whhx = (const float*)d_in[2];
    const float* bihx = (const float*)d_in[3];
    const float* bhhx = (const float*)d_in[4];
    const float* Wihy = (const float*)d_in[5];
    const float* Whhy = (const float*)d_in[6];
    const float* bihy = (const float*)d_in[7];
    const float* bhhy = (const float*)d_in[8];
    _Float16* prex = (_Float16*)d_ws;                          // 33.5MB
    _Float16* prey = prex + (size_t)NSEQ * TLEN * 64;          // 33.5MB
    float* of = (float*)d_out;

    k_proj0 <<<2048, 256, 0, stream>>>(x, Wihx, bihx, bhhx, prex);
    k_scan<0><<<128, 256, 0, stream>>>(prex, Whhx, Wihy, bihy, bhhy, prey, nullptr);
    k_scan<1><<<128, 256, 0, stream>>>(prey, Whhy, nullptr, nullptr, nullptr, nullptr, of);
}